// Round 5
// baseline (976.860 us; speedup 1.0000x reference)
//
#include <hip/hip_runtime.h>
#include <hip/hip_bf16.h>

#define IN_DIM 1024
#define DK 512
#define DV 512
#define NQ 8192
#define NKV 8192
#define BQ 64
#define BK 32

typedef _Float16 f16x8 __attribute__((ext_vector_type(8)));
typedef _Float16 f16x4 __attribute__((ext_vector_type(4)));
typedef float f32x4 __attribute__((ext_vector_type(4)));

// ---------------- projection: out = A @ W^T + b, stored f16 ----------------
// Software-pipelined: register prefetch + LDS double buffer, 1 barrier/iter.
__global__ __launch_bounds__(256, 2) void proj_kernel(
    const float* __restrict__ qin, const float* __restrict__ kin, const float* __restrict__ vin,
    const float* __restrict__ Wq, const float* __restrict__ bq,
    const float* __restrict__ Wk, const float* __restrict__ bk,
    const float* __restrict__ Wv, const float* __restrict__ bv,
    _Float16* __restrict__ Qb, _Float16* __restrict__ Kb, _Float16* __restrict__ Vt)
{
    const int z = blockIdx.z;
    const float* A  = (z == 0) ? qin : (z == 1) ? kin : vin;
    const float* W  = (z == 0) ? Wq  : (z == 1) ? Wk  : Wv;
    const float* bi = (z == 0) ? bq  : (z == 1) ? bk  : bv;

    __shared__ _Float16 As[2][128][72];   // 2 x 18 KB
    __shared__ _Float16 Bs[2][128][72];

    const int tid = threadIdx.x;
    const int rowbase = blockIdx.y * 128;
    const int colbase = blockIdx.x * 128;
    const int wave = tid >> 6;
    const int lane = tid & 63;
    const int quad = lane >> 4;
    const int l16  = lane & 15;
    const int wrow = (wave & 1) * 64;
    const int wcol = (wave >> 1) * 64;

    float4 ra[8], rb[8];

    auto ld = [&](int kc) {
#pragma unroll
        for (int i = 0; i < 8; ++i) {
            int idx = tid + i * 256;
            int row = idx >> 4, c4 = idx & 15;
            ra[i] = *(const float4*)&A[(size_t)(rowbase + row) * IN_DIM + kc * 64 + c4 * 4];
            rb[i] = *(const float4*)&W[(size_t)(colbase + row) * IN_DIM + kc * 64 + c4 * 4];
        }
    };
    auto st = [&](int buf) {
#pragma unroll
        for (int i = 0; i < 8; ++i) {
            int idx = tid + i * 256;
            int row = idx >> 4, c4 = idx & 15;
            f16x4 pa, pb;
            pa[0] = (_Float16)ra[i].x; pa[1] = (_Float16)ra[i].y;
            pa[2] = (_Float16)ra[i].z; pa[3] = (_Float16)ra[i].w;
            pb[0] = (_Float16)rb[i].x; pb[1] = (_Float16)rb[i].y;
            pb[2] = (_Float16)rb[i].z; pb[3] = (_Float16)rb[i].w;
            *(f16x4*)&As[buf][row][c4 * 4] = pa;
            *(f16x4*)&Bs[buf][row][c4 * 4] = pb;
        }
    };

    f32x4 acc[4][4];
#pragma unroll
    for (int r = 0; r < 4; ++r)
#pragma unroll
        for (int c = 0; c < 4; ++c) acc[r][c] = (f32x4)(0.0f);

    ld(0); st(0); ld(1);
    __syncthreads();

    for (int kc = 0; kc < 16; ++kc) {
        const int buf = kc & 1;
#pragma unroll
        for (int ks = 0; ks < 2; ++ks) {
            f16x8 af[4], bfr[4];
#pragma unroll
            for (int r = 0; r < 4; ++r)
                af[r] = *(const f16x8*)&As[buf][wrow + r * 16 + l16][ks * 32 + quad * 8];
#pragma unroll
            for (int c = 0; c < 4; ++c)
                bfr[c] = *(const f16x8*)&Bs[buf][wcol + c * 16 + l16][ks * 32 + quad * 8];
#pragma unroll
            for (int r = 0; r < 4; ++r)
#pragma unroll
                for (int c = 0; c < 4; ++c)
                    acc[r][c] = __builtin_amdgcn_mfma_f32_16x16x32_f16(af[r], bfr[c], acc[r][c], 0, 0, 0);
        }
        if (kc + 1 < 16) st(buf ^ 1);     // waits on loads(kc+1), writes other buffer
        if (kc + 2 < 16) ld(kc + 2);      // flies across barrier + next MFMA phase
        __syncthreads();
    }

    if (z < 2) {
        _Float16* outp = (z == 0) ? Qb : Kb;
#pragma unroll
        for (int c = 0; c < 4; ++c) {
            int col = colbase + wcol + c * 16 + l16;
            float bval = bi[col];
#pragma unroll
            for (int r = 0; r < 4; ++r)
#pragma unroll
                for (int g = 0; g < 4; ++g) {
                    int row = rowbase + wrow + r * 16 + quad * 4 + g;
                    outp[(size_t)row * DK + col] = (_Float16)(acc[r][c][g] + bval);
                }
        }
    } else {
#pragma unroll
        for (int c = 0; c < 4; ++c) {
            int col = colbase + wcol + c * 16 + l16;
            float bval = bi[col];
#pragma unroll
            for (int r = 0; r < 4; ++r) {
                int row0 = rowbase + wrow + r * 16 + quad * 4;
                f16x4 pk;
#pragma unroll
                for (int g = 0; g < 4; ++g) pk[g] = (_Float16)(acc[r][c][g] + bval);
                *(f16x4*)&Vt[(size_t)col * NKV + row0] = pk;
            }
        }
    }
}

// ---- flash attention: dbuf LDS (BK=32) + reg prefetch, 3 barriers/chunk ----
// 8 waves. Wave w: qb=w>>1 (16-q band), kw=w&1 (16-key half) for S;
// dvh=w&1 (256-dv half) for PV. Full-DK S per wave => no partial exchange.
// LDS map (bytes): buf b: K b*74240 [32 x 1040B pad], V b*74240+33280 [512 x 80B pad]
//   Ps 148480 + qb*1280 + row*80 + col*2 ; max 153600 + (qb*2+kw)*64 ; sum 154112 + ...
__global__ __launch_bounds__(512, 2) void flash_kernel(
    const _Float16* __restrict__ Qb, const _Float16* __restrict__ Kb,
    const _Float16* __restrict__ Vt, float* __restrict__ Opart,
    float* __restrict__ Mpart, float* __restrict__ Lpart,
    float* __restrict__ outp, int nsplit, int nchunks, int yshift)
{
    __shared__ __align__(16) char sm[154624];

    const int tid  = threadIdx.x;
    const int w    = tid >> 6;
    const int lane = tid & 63;
    const int quad = lane >> 4;
    const int l16  = lane & 15;
    const int qb   = w >> 1;
    const int kw   = w & 1;
    const int dvh  = w & 1;
    const int bid  = blockIdx.x;
    const int y    = bid & (nsplit - 1);      // partition -> XCD-aligned (bid%8 = XCD)
    const int qbase = (bid >> yshift) * BQ;
    const int keystart = y * nchunks * BK;

    // Q fragments: rows qbase + qb*16 + l16 (A-frag: lane m = l16), full DK
    f16x8 qf[16];
    {
        const _Float16* qp = Qb + (size_t)(qbase + qb * 16 + l16) * DK + quad * 8;
#pragma unroll
        for (int s = 0; s < 16; ++s) qf[s] = *(const f16x8*)(qp + s * 32);
    }

    float mreg[4], lreg[4];
#pragma unroll
    for (int g = 0; g < 4; ++g) { mreg[g] = -1e30f; lreg[g] = 0.0f; }
    f32x4 oacc[16];
#pragma unroll
    for (int ct = 0; ct < 16; ++ct) oacc[ct] = (f32x4)(0.0f);

    uint4 kreg[4], vreg[4];
    // ---- prologue: chunk 0 staged into buffer 0
    {
        const int kpos = keystart;
#pragma unroll
        for (int i = 0; i < 4; ++i) { int u = tid + i * 512; int key = u >> 6, c8 = u & 63;
            kreg[i] = *(const uint4*)&Kb[(size_t)(kpos + key) * DK + c8 * 8]; }
#pragma unroll
        for (int i = 0; i < 4; ++i) { int u = tid + i * 512; int dv = u >> 2, c4 = u & 3;
            vreg[i] = *(const uint4*)&Vt[(size_t)dv * NKV + kpos + c4 * 8]; }
#pragma unroll
        for (int i = 0; i < 4; ++i) { int u = tid + i * 512; int key = u >> 6, c8 = u & 63;
            *(uint4*)(sm + key * 1040 + c8 * 16) = kreg[i]; }
#pragma unroll
        for (int i = 0; i < 4; ++i) { int u = tid + i * 512; int dv = u >> 2, c4 = u & 3;
            *(uint4*)(sm + 33280 + dv * 80 + c4 * 16) = vreg[i]; }
    }
    __syncthreads();

    for (int ch = 0; ch < nchunks; ++ch) {
        char* smc = sm + (ch & 1) * 74240;

        // ---- prefetch chunk ch+1 into regs (consumed at the write below)
        if (ch + 1 < nchunks) {
            const int kpos = keystart + (ch + 1) * BK;
#pragma unroll
            for (int i = 0; i < 4; ++i) { int u = tid + i * 512; int key = u >> 6, c8 = u & 63;
                kreg[i] = *(const uint4*)&Kb[(size_t)(kpos + key) * DK + c8 * 8]; }
#pragma unroll
            for (int i = 0; i < 4; ++i) { int u = tid + i * 512; int dv = u >> 2, c4 = u & 3;
                vreg[i] = *(const uint4*)&Vt[(size_t)dv * NKV + kpos + c4 * 8]; }
        }

        // ---- S: 16 q x 16 keys, full DK (16 MFMA)
        f32x4 s = (f32x4)(0.0f);
        {
            const char* kp = smc + (kw * 16 + l16) * 1040 + quad * 16;
#pragma unroll
            for (int st = 0; st < 16; ++st) {
                f16x8 kf = *(const f16x8*)(kp + st * 64);
                s = __builtin_amdgcn_mfma_f32_16x16x32_f16(qf[st], kf, s, 0, 0, 0);
            }
        }

        // ---- per-row tile max over 16 keys (l16 lanes)
        float mt[4];
#pragma unroll
        for (int g = 0; g < 4; ++g) {
            float m = s[g];
            m = fmaxf(m, __shfl_xor(m, 1));
            m = fmaxf(m, __shfl_xor(m, 2));
            m = fmaxf(m, __shfl_xor(m, 4));
            m = fmaxf(m, __shfl_xor(m, 8));
            mt[g] = m;
        }
        if (l16 == 0) {
            float* mp = (float*)(sm + 153600 + (qb * 2 + kw) * 64);
#pragma unroll
            for (int g = 0; g < 4; ++g) mp[quad * 4 + g] = mt[g];
        }
        __syncthreads();   // B2

        // ---- combine max (replicated per pair), exp, Ps write, partial sums
        const float* mp0 = (const float*)(sm + 153600 + (qb * 2) * 64);
        const float* mp1 = (const float*)(sm + 153600 + (qb * 2 + 1) * 64);
        float alpha[4];
#pragma unroll
        for (int g = 0; g < 4; ++g) {
            const int r = quad * 4 + g;
            float mn = fmaxf(mreg[g], fmaxf(mp0[r], mp1[r]));
            alpha[g] = __expf(mreg[g] - mn);
            mreg[g] = mn;
            float p = __expf(s[g] - mn);
            *(_Float16*)(sm + 148480 + qb * 1280 + r * 80 + (kw * 16 + l16) * 2) = (_Float16)p;
            float ts = p;
            ts += __shfl_xor(ts, 1);
            ts += __shfl_xor(ts, 2);
            ts += __shfl_xor(ts, 4);
            ts += __shfl_xor(ts, 8);
            if (l16 == 0) ((float*)(sm + 154112 + (qb * 2 + kw) * 64))[r] = ts;
        }
        __syncthreads();   // B3

        const float* sp0 = (const float*)(sm + 154112 + (qb * 2) * 64);
        const float* sp1 = (const float*)(sm + 154112 + (qb * 2 + 1) * 64);
#pragma unroll
        for (int g = 0; g < 4; ++g) {
            const int r = quad * 4 + g;
            lreg[g] = lreg[g] * alpha[g] + sp0[r] + sp1[r];
        }
#pragma unroll
        for (int ct = 0; ct < 16; ++ct)
#pragma unroll
            for (int g = 0; g < 4; ++g) oacc[ct][g] *= alpha[g];

        // ---- stage chunk ch+1 into the other buffer (overlaps PV across waves)
        if (ch + 1 < nchunks) {
            char* smn = sm + ((ch + 1) & 1) * 74240;
#pragma unroll
            for (int i = 0; i < 4; ++i) { int u = tid + i * 512; int key = u >> 6, c8 = u & 63;
                *(uint4*)(smn + key * 1040 + c8 * 16) = kreg[i]; }
#pragma unroll
            for (int i = 0; i < 4; ++i) { int u = tid + i * 512; int dv = u >> 2, c4 = u & 3;
                *(uint4*)(smn + 33280 + dv * 80 + c4 * 16) = vreg[i]; }
        }

        // ---- PV: one A-frag (this band's P), 16 V tiles, K=32 in one MFMA
        {
            f16x8 pa = *(const f16x8*)(sm + 148480 + qb * 1280 + l16 * 80 + quad * 16);
            const char* vp = smc + 33280 + (dvh * 256 + l16) * 80 + quad * 16;
#pragma unroll
            for (int ct = 0; ct < 16; ++ct) {
                f16x8 vf = *(const f16x8*)(vp + ct * 1280);
                oacc[ct] = __builtin_amdgcn_mfma_f32_16x16x32_f16(pa, vf, oacc[ct], 0, 0, 0);
            }
        }
        __syncthreads();   // boundary: next buffer ready + this buffer consumed
    }

    const float norm = 0.044194173824159216f;   // 1/sqrt(512), applied AFTER softmax
    if (nsplit == 1) {
#pragma unroll
        for (int g = 0; g < 4; ++g) {
            const int row = qbase + qb * 16 + quad * 4 + g;
            const float sc = norm / lreg[g];
#pragma unroll
            for (int ct = 0; ct < 16; ++ct)
                outp[(size_t)row * DV + dvh * 256 + ct * 16 + l16] = oacc[ct][g] * sc;
        }
    } else {
        float* op = Opart + (size_t)y * NQ * DV;
#pragma unroll
        for (int g = 0; g < 4; ++g) {
            const int row = qbase + qb * 16 + quad * 4 + g;
#pragma unroll
            for (int ct = 0; ct < 16; ++ct)
                op[(size_t)row * DV + dvh * 256 + ct * 16 + l16] = oacc[ct][g];
        }
        if (kw == 0 && l16 == 0) {
#pragma unroll
            for (int g = 0; g < 4; ++g) {
                const int row = qbase + qb * 16 + quad * 4 + g;
                Mpart[(size_t)y * NQ + row] = mreg[g];
                Lpart[(size_t)y * NQ + row] = lreg[g];
            }
        }
    }
}

// ---------------- combine KV-split partials -------------------------------
__global__ __launch_bounds__(512) void reduce_kernel(
    const float* __restrict__ Opart, const float* __restrict__ Mpart,
    const float* __restrict__ Lpart, float* __restrict__ outp, int nsplit)
{
    const int tid = threadIdx.x;
    const int row = blockIdx.x * 32 + (tid >> 4);
    const int cb  = (tid & 15) * 4;

    float M = -1e30f;
    for (int s = 0; s < nsplit; ++s)
        M = fmaxf(M, Mpart[(size_t)s * NQ + row]);
    float e[4];
    float L = 0.0f;
    for (int s = 0; s < nsplit; ++s) {
        e[s] = __expf(Mpart[(size_t)s * NQ + row] - M);
        L += Lpart[(size_t)s * NQ + row] * e[s];
    }
    const float r = 0.044194173824159216f / L;

    const float* base = Opart + (size_t)row * DV + cb;
    float* ob = outp + (size_t)row * DV + cb;
#pragma unroll
    for (int i = 0; i < 8; ++i) {
        float4 o = make_float4(0.f, 0.f, 0.f, 0.f);
        for (int s = 0; s < nsplit; ++s) {
            float4 a = *(const float4*)(base + (size_t)s * NQ * DV + i * 64);
            o.x += a.x * e[s]; o.y += a.y * e[s]; o.z += a.z * e[s]; o.w += a.w * e[s];
        }
        o.x *= r; o.y *= r; o.z *= r; o.w *= r;
        *(float4*)(ob + i * 64) = o;
    }
}

extern "C" void kernel_launch(void* const* d_in, const int* in_sizes, int n_in,
                              void* d_out, int out_size, void* d_ws, size_t ws_size,
                              hipStream_t stream) {
    const float* q  = (const float*)d_in[0];
    const float* k  = (const float*)d_in[1];
    const float* v  = (const float*)d_in[2];
    const float* Wq = (const float*)d_in[3];
    const float* bq = (const float*)d_in[4];
    const float* Wk = (const float*)d_in[5];
    const float* bk = (const float*)d_in[6];
    const float* Wv = (const float*)d_in[7];
    const float* bv = (const float*)d_in[8];

    _Float16* Qb = (_Float16*)d_ws;                 // 8 MB
    _Float16* Kb = Qb + (size_t)NQ * DK;            // 8 MB
    _Float16* Vt = Kb + (size_t)NKV * DK;           // 8 MB
    const size_t base = 3 * (size_t)NQ * DK * sizeof(_Float16);
    float* Mpart = (float*)((char*)d_ws + base);
    float* Lpart = Mpart + 4 * NQ;
    float* Opart = Lpart + 4 * NQ;
    const size_t per_split = (size_t)NQ * DV * sizeof(float);  // 16 MB

    int nsplit = 1, yshift = 0;
    if (ws_size >= base + 262144 + 2 * per_split) { nsplit = 2; yshift = 1; }
    const int nchunks = NKV / (nsplit * BK);
    float* outp = (float*)d_out;

    proj_kernel<<<dim3(DK / 128, NQ / 128, 3), 256, 0, stream>>>(
        q, k, v, Wq, bq, Wk, bk, Wv, bv, Qb, Kb, Vt);
    flash_kernel<<<dim3((NQ / BQ) * nsplit), 512, 0, stream>>>(
        Qb, Kb, Vt, Opart, Mpart, Lpart, outp, nsplit, nchunks, yshift);
    if (nsplit > 1)
        reduce_kernel<<<dim3(NQ / 32), 512, 0, stream>>>(Opart, Mpart, Lpart, outp, nsplit);
}

// Round 6
// 692.051 us; speedup vs baseline: 1.4115x; 1.4115x over previous
//
#include <hip/hip_runtime.h>
#include <hip/hip_bf16.h>

#define IN_DIM 1024
#define DK 512
#define DV 512
#define NQ 8192
#define NKV 8192

typedef _Float16 f16x8 __attribute__((ext_vector_type(8)));
typedef _Float16 f16x4 __attribute__((ext_vector_type(4)));
typedef float f32x4 __attribute__((ext_vector_type(4)));

// ---------------- projection: out = A @ W^T + b -----------------------------
// Outputs in MFMA-fragment-major layout (frag = 64 lanes x 16 B = 1 KB):
//  Q'/K': frag fi = n_tile*16 + k_step; element [n = tile*16+l16][k = step*32+quad*8+j]
//  V'   : frag fi = (chunk*32 + dv_tile)*2 + kst;
//         element [key = chunk*64+kst*32+quad*8+j][dv = dv_tile*16+l16]
__global__ __launch_bounds__(256, 2) void proj_kernel(
    const float* __restrict__ qin, const float* __restrict__ kin, const float* __restrict__ vin,
    const float* __restrict__ Wq, const float* __restrict__ bq,
    const float* __restrict__ Wk, const float* __restrict__ bk,
    const float* __restrict__ Wv, const float* __restrict__ bv,
    _Float16* __restrict__ Qp, _Float16* __restrict__ Kp, _Float16* __restrict__ Vp)
{
    const int z = blockIdx.z;
    const float* A  = (z == 0) ? qin : (z == 1) ? kin : vin;
    const float* W  = (z == 0) ? Wq  : (z == 1) ? Wk  : Wv;
    const float* bi = (z == 0) ? bq  : (z == 1) ? bk  : bv;

    __shared__ __align__(16) char psm[73728];
    _Float16 (*As)[128][72] = (_Float16(*)[128][72])psm;           // [2][128][72]
    _Float16 (*Bs)[128][72] = (_Float16(*)[128][72])(psm + 36864);
    _Float16* trans = (_Float16*)psm;   // [128][152] = 38912 B, reused post-loop

    const int tid = threadIdx.x;
    const int rowbase = blockIdx.y * 128;
    const int colbase = blockIdx.x * 128;
    const int wave = tid >> 6;
    const int lane = tid & 63;
    const int quad = lane >> 4;
    const int l16  = lane & 15;
    const int wrow = (wave & 1) * 64;
    const int wcol = (wave >> 1) * 64;

    float4 ra[8], rb[8];
    auto ld = [&](int kc) {
#pragma unroll
        for (int i = 0; i < 8; ++i) {
            int idx = tid + i * 256;
            int row = idx >> 4, c4 = idx & 15;
            ra[i] = *(const float4*)&A[(size_t)(rowbase + row) * IN_DIM + kc * 64 + c4 * 4];
            rb[i] = *(const float4*)&W[(size_t)(colbase + row) * IN_DIM + kc * 64 + c4 * 4];
        }
    };
    auto st = [&](int buf) {
#pragma unroll
        for (int i = 0; i < 8; ++i) {
            int idx = tid + i * 256;
            int row = idx >> 4, c4 = idx & 15;
            f16x4 pa, pb;
            pa[0] = (_Float16)ra[i].x; pa[1] = (_Float16)ra[i].y;
            pa[2] = (_Float16)ra[i].z; pa[3] = (_Float16)ra[i].w;
            pb[0] = (_Float16)rb[i].x; pb[1] = (_Float16)rb[i].y;
            pb[2] = (_Float16)rb[i].z; pb[3] = (_Float16)rb[i].w;
            *(f16x4*)&As[buf][row][c4 * 4] = pa;
            *(f16x4*)&Bs[buf][row][c4 * 4] = pb;
        }
    };

    f32x4 acc[4][4];
#pragma unroll
    for (int r = 0; r < 4; ++r)
#pragma unroll
        for (int c = 0; c < 4; ++c) acc[r][c] = (f32x4)(0.0f);

    ld(0); st(0); ld(1);
    __syncthreads();

    for (int kc = 0; kc < 16; ++kc) {
        const int buf = kc & 1;
#pragma unroll
        for (int ks = 0; ks < 2; ++ks) {
            f16x8 af[4], bfr[4];
#pragma unroll
            for (int r = 0; r < 4; ++r)
                af[r] = *(const f16x8*)&As[buf][wrow + r * 16 + l16][ks * 32 + quad * 8];
#pragma unroll
            for (int c = 0; c < 4; ++c)
                bfr[c] = *(const f16x8*)&Bs[buf][wcol + c * 16 + l16][ks * 32 + quad * 8];
#pragma unroll
            for (int r = 0; r < 4; ++r)
#pragma unroll
                for (int c = 0; c < 4; ++c)
                    acc[r][c] = __builtin_amdgcn_mfma_f32_16x16x32_f16(af[r], bfr[c], acc[r][c], 0, 0, 0);
        }
        if (kc + 1 < 16) st(buf ^ 1);
        if (kc + 2 < 16) ld(kc + 2);
        __syncthreads();
    }
    // loop-ending barrier: LDS now dead, reuse as `trans`

    const int S = 152;   // row stride (f16); 304 B -> 2-way max bank aliasing
    if (z < 2) {
        _Float16* outp = (z == 0) ? Qp : Kp;
#pragma unroll
        for (int c = 0; c < 4; ++c) {
            int col = wcol + c * 16 + l16;          // local dk
            float bval = bi[colbase + col];
#pragma unroll
            for (int r = 0; r < 4; ++r)
#pragma unroll
                for (int g = 0; g < 4; ++g) {
                    int row = wrow + r * 16 + quad * 4 + g;   // local n (q or key)
                    trans[row * S + col] = (_Float16)(acc[r][c][g] + bval);
                }
        }
        __syncthreads();
#pragma unroll
        for (int i = 0; i < 2; ++i)
#pragma unroll
            for (int stp = 0; stp < 4; ++stp) {
                int tl = wave * 2 + i;
                f16x8 v = *(const f16x8*)&trans[(tl * 16 + l16) * S + stp * 32 + quad * 8];
                size_t fi = (size_t)((blockIdx.y * 8 + tl) * 16 + (blockIdx.x * 4 + stp));
                *(f16x8*)&outp[fi * 512 + lane * 8] = v;
            }
    } else {
        // stage TRANSPOSED: trans[dv][key] so V' frag reads are contiguous
#pragma unroll
        for (int c = 0; c < 4; ++c) {
            int dv = wcol + c * 16 + l16;
            float bval = bi[colbase + dv];
#pragma unroll
            for (int r = 0; r < 4; ++r)
#pragma unroll
                for (int g = 0; g < 4; ++g) {
                    int key = wrow + r * 16 + quad * 4 + g;
                    trans[dv * S + key] = (_Float16)(acc[r][c][g] + bval);
                }
        }
        __syncthreads();
#pragma unroll
        for (int i = 0; i < 2; ++i)
#pragma unroll
            for (int chl = 0; chl < 2; ++chl)
#pragma unroll
                for (int kst = 0; kst < 2; ++kst) {
                    int tdl = wave * 2 + i;
                    f16x8 v = *(const f16x8*)&trans[(tdl * 16 + l16) * S + chl * 64 + kst * 32 + quad * 8];
                    size_t fi = ((size_t)(blockIdx.y * 2 + chl) * 32 + (blockIdx.x * 8 + tdl)) * 2 + kst;
                    *(f16x8*)&Vp[fi * 512 + lane * 8] = v;
                }
    }
}

// ---- flash attention: zero-LDS operands (frag-major global streams) -------
// 4 waves, 1 wave/SIMD (512-VGPR budget). Wave w: key-slice w (S), dv-slice
// w*128 (PV). Q in regs. Only P + softmax stats go through LDS.
__global__ __launch_bounds__(256, 1) void flash_kernel(
    const _Float16* __restrict__ Qp, const _Float16* __restrict__ Kp,
    const _Float16* __restrict__ Vp, float* __restrict__ outp)
{
    __shared__ _Float16 Ps[32][72];   // 4608 B
    __shared__ float Smax[4][32];
    __shared__ float Ssum[4][32];

    const int tid  = threadIdx.x;
    const int w    = tid >> 6;
    const int lane = tid & 63;
    const int quad = lane >> 4;
    const int l16  = lane & 15;
    const int qbase = blockIdx.x * 32;

    // ---- Q fragments (A-layout), whole DK, 2 q-bands: 128 VGPRs
    f16x8 qf[2][16];
    {
        const _Float16* qp = Qp + (size_t)qbase * 512 + lane * 8;
#pragma unroll
        for (int qt = 0; qt < 2; ++qt)
#pragma unroll
            for (int stp = 0; stp < 16; ++stp)
                qf[qt][stp] = *(const f16x8*)(qp + (size_t)(qt * 16 + stp) * 512);
    }

    float mreg[2][4], lreg[2][4];
#pragma unroll
    for (int qt = 0; qt < 2; ++qt)
#pragma unroll
        for (int g = 0; g < 4; ++g) { mreg[qt][g] = -1e30f; lreg[qt][g] = 0.0f; }
    f32x4 oacc[2][8];
#pragma unroll
    for (int qt = 0; qt < 2; ++qt)
#pragma unroll
        for (int ct = 0; ct < 8; ++ct) oacc[qt][ct] = (f32x4)(0.0f);

    const _Float16* kfp = Kp + (size_t)w * 16 * 512 + lane * 8;   // + ch*32768
    const _Float16* vfp = Vp + (size_t)w * 8192 + lane * 8;       // + ch*32768

    // ---- prologue: K fragments for chunk 0 (wave's 16-key slice, full DK)
    f16x8 kf[16];
#pragma unroll
    for (int stp = 0; stp < 16; ++stp)
        kf[stp] = *(const f16x8*)(kfp + stp * 512);

    f16x8 vf[16];

    for (int ch = 0; ch < 128; ++ch) {
        // ---- issue V loads for THIS chunk (consumed in PV, ~800 cyc away)
        const _Float16* vp = vfp + (size_t)ch * 32768;
#pragma unroll
        for (int i = 0; i < 16; ++i)
            vf[i] = *(const f16x8*)(vp + i * 512);

        // ---- S: 32 q x 16 keys (this wave's slice), full DK
        f32x4 s0 = (f32x4)(0.0f), s1 = (f32x4)(0.0f);
#pragma unroll
        for (int stp = 0; stp < 16; ++stp) {
            s0 = __builtin_amdgcn_mfma_f32_16x16x32_f16(qf[0][stp], kf[stp], s0, 0, 0, 0);
            s1 = __builtin_amdgcn_mfma_f32_16x16x32_f16(qf[1][stp], kf[stp], s1, 0, 0, 0);
        }

        // ---- slice row-max (16 lanes = 16 keys)
        if (l16 == 0) { }   // (placeholder to keep structure clear)
        float mx0[4], mx1[4];
#pragma unroll
        for (int g = 0; g < 4; ++g) {
            float m0 = s0[g], m1 = s1[g];
            m0 = fmaxf(m0, __shfl_xor(m0, 1)); m1 = fmaxf(m1, __shfl_xor(m1, 1));
            m0 = fmaxf(m0, __shfl_xor(m0, 2)); m1 = fmaxf(m1, __shfl_xor(m1, 2));
            m0 = fmaxf(m0, __shfl_xor(m0, 4)); m1 = fmaxf(m1, __shfl_xor(m1, 4));
            m0 = fmaxf(m0, __shfl_xor(m0, 8)); m1 = fmaxf(m1, __shfl_xor(m1, 8));
            mx0[g] = m0; mx1[g] = m1;
        }
        if (l16 == 0) {
#pragma unroll
            for (int g = 0; g < 4; ++g) {
                Smax[w][quad * 4 + g]      = mx0[g];
                Smax[w][16 + quad * 4 + g] = mx1[g];
            }
        }
        __syncthreads();   // B1

        // ---- combine max, exp, write P (f16), slice sums
        float alpha[2][4];
#pragma unroll
        for (int qt = 0; qt < 2; ++qt)
#pragma unroll
            for (int g = 0; g < 4; ++g) {
                const int row = qt * 16 + quad * 4 + g;
                float mt = fmaxf(fmaxf(Smax[0][row], Smax[1][row]),
                                 fmaxf(Smax[2][row], Smax[3][row]));
                float mn = fmaxf(mreg[qt][g], mt);
                alpha[qt][g] = __expf(mreg[qt][g] - mn);
                mreg[qt][g] = mn;
                float p = __expf(((qt == 0) ? s0[g] : s1[g]) - mn);
                Ps[row][w * 16 + l16] = (_Float16)p;
                float ts = p;
                ts += __shfl_xor(ts, 1);
                ts += __shfl_xor(ts, 2);
                ts += __shfl_xor(ts, 4);
                ts += __shfl_xor(ts, 8);
                if (l16 == 0) Ssum[w][row] = ts;
            }
        __syncthreads();   // B2

        // ---- l update + O rescale
#pragma unroll
        for (int qt = 0; qt < 2; ++qt)
#pragma unroll
            for (int g = 0; g < 4; ++g) {
                const int row = qt * 16 + quad * 4 + g;
                float lsum = (Ssum[0][row] + Ssum[1][row]) + (Ssum[2][row] + Ssum[3][row]);
                lreg[qt][g] = lreg[qt][g] * alpha[qt][g] + lsum;
            }
#pragma unroll
        for (int qt = 0; qt < 2; ++qt)
#pragma unroll
            for (int ct = 0; ct < 8; ++ct)
#pragma unroll
                for (int g = 0; g < 4; ++g) oacc[qt][ct][g] *= alpha[qt][g];

        // ---- issue K loads for chunk ch+1 (kf fully consumed by S above)
        if (ch + 1 < 128) {
            const _Float16* kp = kfp + (size_t)(ch + 1) * 32768;
#pragma unroll
            for (int stp = 0; stp < 16; ++stp)
                kf[stp] = *(const f16x8*)(kp + stp * 512);
        }

        // ---- PV: P A-frags from LDS, V frags from registers
        f16x8 pa[2][2];
#pragma unroll
        for (int qt = 0; qt < 2; ++qt)
#pragma unroll
            for (int kst = 0; kst < 2; ++kst)
                pa[qt][kst] = *(const f16x8*)&Ps[qt * 16 + l16][kst * 32 + quad * 8];
#pragma unroll
        for (int ct = 0; ct < 8; ++ct)
#pragma unroll
            for (int kst = 0; kst < 2; ++kst) {
                oacc[0][ct] = __builtin_amdgcn_mfma_f32_16x16x32_f16(pa[0][kst], vf[ct * 2 + kst], oacc[0][ct], 0, 0, 0);
                oacc[1][ct] = __builtin_amdgcn_mfma_f32_16x16x32_f16(pa[1][kst], vf[ct * 2 + kst], oacc[1][ct], 0, 0, 0);
            }
    }

    // ---- epilogue: normalize + post-softmax scale, direct store
    const float norm = 0.044194173824159216f;   // 1/sqrt(512)
#pragma unroll
    for (int qt = 0; qt < 2; ++qt)
#pragma unroll
        for (int g = 0; g < 4; ++g) {
            const int row = qbase + qt * 16 + quad * 4 + g;
            const float sc = norm / lreg[qt][g];
#pragma unroll
            for (int ct = 0; ct < 8; ++ct)
                outp[(size_t)row * 512 + w * 128 + ct * 16 + l16] = oacc[qt][ct][g] * sc;
        }
}

extern "C" void kernel_launch(void* const* d_in, const int* in_sizes, int n_in,
                              void* d_out, int out_size, void* d_ws, size_t ws_size,
                              hipStream_t stream) {
    const float* q  = (const float*)d_in[0];
    const float* k  = (const float*)d_in[1];
    const float* v  = (const float*)d_in[2];
    const float* Wq = (const float*)d_in[3];
    const float* bq = (const float*)d_in[4];
    const float* Wk = (const float*)d_in[5];
    const float* bk = (const float*)d_in[6];
    const float* Wv = (const float*)d_in[7];
    const float* bv = (const float*)d_in[8];

    _Float16* Qp = (_Float16*)d_ws;                 // 8 MB, frag-major
    _Float16* Kp = Qp + (size_t)NQ * DK;            // 8 MB, frag-major
    _Float16* Vp = Kp + (size_t)NKV * DK;           // 8 MB, frag-major
    float* outp = (float*)d_out;

    proj_kernel<<<dim3(DK / 128, NQ / 128, 3), 256, 0, stream>>>(
        q, k, v, Wq, bq, Wk, bk, Wv, bv, Qp, Kp, Vp);
    flash_kernel<<<dim3(NQ / 32), 256, 0, stream>>>(Qp, Kp, Vp, outp);
}